// Round 11
// baseline (135.013 us; speedup 1.0000x reference)
//
#include <hip/hip_runtime.h>
#include <math.h>

#define HID 4096
#define NEXP 64
#define NTOK 16384
#define PSTRIDE 68  // partial row stride (floats): 4*68 % 32 == 16 -> 2-way free

typedef __attribute__((ext_vector_type(8))) short short8;
typedef __attribute__((ext_vector_type(8))) __bf16 bf16x8;
typedef __attribute__((ext_vector_type(4))) float f32x4;

// ---- Kernel 0: W[k][e] fp32 -> hi/lo bf16, B-fragment-linear (also zeroes
// the flag counter so no memset node is needed in the graph).
__global__ __launch_bounds__(256) void wfrag_kernel(
    const float* __restrict__ W, short* __restrict__ wfh,
    short* __restrict__ wfl, unsigned int* __restrict__ flag_count) {
  if (blockIdx.x == 0 && threadIdx.x == 0) *flag_count = 0u;
  int gid = blockIdx.x * 256 + threadIdx.x;  // 0 .. 32767
  int l  = gid & 63;
  int nt = (gid >> 6) & 3;
  int ks = gid >> 8;                         // 0 .. 127
  int e  = nt * 16 + (l & 15);
  int k0 = ks * 32 + (l >> 4) * 8;
  bf16x8 h8, l8;
#pragma unroll
  for (int j = 0; j < 8; ++j) {
    float w = W[(size_t)(k0 + j) * NEXP + e];
    __bf16 h = (__bf16)w;         // RNE
    h8[j] = h;
    l8[j] = (__bf16)(w - (float)h);
  }
  ((short8*)wfh)[gid] = __builtin_bit_cast(short8, h8);
  ((short8*)wfl)[gid] = __builtin_bit_cast(short8, l8);
}

// ---------------- gemm helpers (parity P is a compile-time literal) ---------
template <int P>
__device__ __forceinline__ void issue_b(const short8*& wh, const short8*& wl,
                                        short8 (&rbh)[2][8],
                                        short8 (&rbl)[2][8]) {
#pragma unroll
  for (int kk = 0; kk < 2; ++kk)
#pragma unroll
    for (int nt = 0; nt < 4; ++nt) {
      rbh[P][kk * 4 + nt] = wh[kk * 256 + nt * 64];
      rbl[P][kk * 4 + nt] = wl[kk * 256 + nt * 64];
    }
  wh += 512;
  wl += 512;
}

template <int P>
__device__ __forceinline__ void issue_g(const float* (&xp)[4][2],
                                        float* stage /* wave parity base */) {
#pragma unroll
  for (int st = 0; st < 4; ++st)
#pragma unroll
    for (int n = 0; n < 4; ++n)
      __builtin_amdgcn_global_load_lds(xp[st][n & 1] + (n >> 1) * (8 * HID),
                                       stage + st * 1024 + n * 256, 16, 0, 0);
#pragma unroll
  for (int st = 0; st < 4; ++st) {
    xp[st][0] += 64;
    xp[st][1] += 64;
  }
}

template <int P>
__device__ __forceinline__ void compute_c(const float* stage,
                                          short8 (&rbh)[2][8],
                                          short8 (&rbl)[2][8],
                                          f32x4 (&acc)[4][4], int l) {
  const int lr = l >> 4;
  const char* cb = (const char*)stage;
#pragma unroll
  for (int kk = 0; kk < 2; ++kk) {
    int s0 = ((kk * 8 + lr * 2) ^ (l & 7)) * 16;
#pragma unroll
    for (int st = 0; st < 4; ++st) {
      const char* rowbase = cb + st * 4096 + (l & 15) * 256;
      float4 lo = *(const float4*)(rowbase + s0);
      float4 hi = *(const float4*)(rowbase + (s0 ^ 16));
      float xv[8] = {lo.x, lo.y, lo.z, lo.w, hi.x, hi.y, hi.z, hi.w};
      bf16x8 ah, al;
#pragma unroll
      for (int j = 0; j < 8; ++j) {
        __bf16 h = (__bf16)xv[j];
        ah[j] = h;
        al[j] = (__bf16)(xv[j] - (float)h);
      }
#pragma unroll
      for (int nt = 0; nt < 4; ++nt) {
        bf16x8 vh = __builtin_bit_cast(bf16x8, rbh[P][kk * 4 + nt]);
        bf16x8 vl = __builtin_bit_cast(bf16x8, rbl[P][kk * 4 + nt]);
        acc[st][nt] = __builtin_amdgcn_mfma_f32_16x16x32_bf16(ah, vh, acc[st][nt], 0, 0, 0);
        acc[st][nt] = __builtin_amdgcn_mfma_f32_16x16x32_bf16(al, vh, acc[st][nt], 0, 0, 0);
        acc[st][nt] = __builtin_amdgcn_mfma_f32_16x16x32_bf16(ah, vl, acc[st][nt], 0, 0, 0);
        acc[st][nt] = __builtin_amdgcn_mfma_f32_16x16x32_bf16(al, vl, acc[st][nt], 0, 0, 0);
      }
    }
  }
}

#define SB __builtin_amdgcn_sched_barrier(0)
#define WAIT32 asm volatile("s_waitcnt vmcnt(32)" ::: "memory")
#define WAIT0  asm volatile("s_waitcnt vmcnt(0)" ::: "memory")

// ---- Kernel 1: fused MFMA GEMM + cross-q LDS reduction + fp32 routing ------
// Wave = 64 tokens x K-quarter; counted-vmcnt pipeline as R10. After the
// K-loop, partial 16x64x4q tiles meet in LDS (reusing xstage memory, barrier
// protected), then each wave routes 16 tokens. No partial global round-trip,
// no separate route kernel.
__global__ __launch_bounds__(256) void gemm_route_kernel(
    const float* __restrict__ x, const short* __restrict__ wfh,
    const short* __restrict__ wfl, const float* __restrict__ b,
    float* __restrict__ out_exp, float* __restrict__ out_prob,
    float* __restrict__ out_k, unsigned int* __restrict__ flag_count,
    int* __restrict__ flag_list) {
  __shared__ float smem[32768];  // 128 KB: xstage[4][2][4096], later partials

  const int t = threadIdx.x;
  const int q = t >> 6;    // wave = K-quarter
  const int l = t & 63;
  const int lr = l >> 4;
  const int m0 = blockIdx.x * 64;
  const int kq = q * (HID / 4);

  float* stage0 = smem + q * 8192;         // parity 0
  float* stage1 = smem + q * 8192 + 4096;  // parity 1

  // glds sources: subtile st, instr n: row = m0+st*16+4*(n&1)... (R10 layout)
  const float* xp[4][2];
#pragma unroll
  for (int st = 0; st < 4; ++st)
#pragma unroll
    for (int p = 0; p < 2; ++p) {
      int g = (l & 15) ^ (lr + 4 * p);
      int row = m0 + st * 16 + 4 * p + lr;
      xp[st][p] = x + (size_t)row * HID + kq + g * 4;
    }

  const short8* wh = (const short8*)wfh + (size_t)(q * 32) * 256 + l;
  const short8* wl = (const short8*)wfl + (size_t)(q * 32) * 256 + l;

  f32x4 acc[4][4];
#pragma unroll
  for (int st = 0; st < 4; ++st)
#pragma unroll
    for (int nt = 0; nt < 4; ++nt) acc[st][nt] = (f32x4){0.f, 0.f, 0.f, 0.f};

  short8 rbh[2][8], rbl[2][8];

  // prologue: chunk 0 -> parity 0
  issue_b<0>(wh, wl, rbh, rbl);
  SB;
  issue_g<0>(xp, stage0);
  SB;

#pragma unroll 1
  for (int c2 = 0; c2 < 7; ++c2) {  // chunks 2*c2 and 2*c2+1
    issue_b<1>(wh, wl, rbh, rbl);
    SB;
    issue_g<1>(xp, stage1);
    SB;
    WAIT32;
    SB;
    compute_c<0>(stage0, rbh, rbl, acc, l);

    issue_b<0>(wh, wl, rbh, rbl);
    SB;
    issue_g<0>(xp, stage0);
    SB;
    WAIT32;
    SB;
    compute_c<1>(stage1, rbh, rbl, acc, l);
  }
  // chunk 14: issue 15, drain 14, compute 14; then drain+compute 15
  issue_b<1>(wh, wl, rbh, rbl);
  SB;
  issue_g<1>(xp, stage1);
  SB;
  WAIT32;
  SB;
  compute_c<0>(stage0, rbh, rbl, acc, l);
  WAIT0;
  SB;
  compute_c<1>(stage1, rbh, rbl, acc, l);

  // ---- cross-q reduction in LDS (reuse xstage memory; all reads done) ----
  __syncthreads();
  float* part = smem;  // [4][64][PSTRIDE] = 69.6 KB
#pragma unroll
  for (int st = 0; st < 4; ++st)
#pragma unroll
    for (int nt = 0; nt < 4; ++nt)
#pragma unroll
      for (int r = 0; r < 4; ++r)
        part[(q * 64 + st * 16 + lr * 4 + r) * PSTRIDE + nt * 16 + (l & 15)] =
            acc[st][nt][r];
  __syncthreads();

  // ---------------- routing: wave q handles tokens q*16 .. q*16+15 --------
  const float bias = b[l];
  for (int it = 0; it < 16; ++it) {
    const int tl = q * 16 + it;
    float lgv = (part[(0 * 64 + tl) * PSTRIDE + l] +
                 part[(1 * 64 + tl) * PSTRIDE + l]) +
                (part[(2 * 64 + tl) * PSTRIDE + l] +
                 part[(3 * 64 + tl) * PSTRIDE + l]) +
                bias;

    float mx = lgv;
#pragma unroll
    for (int off = 32; off; off >>= 1) mx = fmaxf(mx, __shfl_xor(mx, off));
    float ev = expf(lgv - mx);
    float sm = ev;
#pragma unroll
    for (int off = 32; off; off >>= 1) sm += __shfl_xor(sm, off);
    float p = ev / sm;

    // bitonic sort: descending by p, ties by ascending index
    float sp = p;
    int   si = l;
#pragma unroll
    for (int k = 2; k <= 64; k <<= 1) {
#pragma unroll
      for (int j = k >> 1; j > 0; j >>= 1) {
        float op = __shfl_xor(sp, j);
        int   oi = __shfl_xor(si, j);
        bool cmp  = (sp > op) || (sp == op && si < oi);
        bool keep = (cmp == (((l & k) == 0) == ((l & j) == 0)));
        if (!keep) { sp = op; si = oi; }
      }
    }

    // inclusive prefix sum
    float c = sp;
#pragma unroll
    for (int off = 1; off < 64; off <<= 1) {
      float tp = __shfl_up(c, off);
      if (l >= off) c += tp;
    }

    unsigned long long m = __ballot(c >= 0.8f);
    int kv = (m == 0ULL) ? NEXP : __ffsll(m);

    // ambiguity flags (margins >> split-bf16 logit error ~2e-5)
    float spn = __shfl_down(sp, 1);
    bool pairRisk = (l < kv) && (l < 63) && ((sp - spn) < 1e-3f * (sp + spn));
    bool cumRisk  = fabsf(c - 0.8f) < 3e-4f;
    bool flagged  = (__ballot(pairRisk || cumRisk) != 0ULL);

    bool sel = l < kv;
    const int tok = m0 + tl;
    size_t base = (size_t)tok * NEXP;
    out_exp[base + l]  = sel ? (float)si : -1.0f;
    out_prob[base + l] = sel ? sp : 0.0f;
    if (l == 0) {
      out_k[tok] = (float)kv;
      if (flagged) {
        unsigned int idx = atomicAdd(flag_count, 1u);
        flag_list[idx] = tok;
      }
    }
  }
}

// ---- Kernel 2: fp64 exact repair of flagged tokens -------------------------
__global__ __launch_bounds__(256) void router_repair(
    const float* __restrict__ x, const float* __restrict__ W,
    const float* __restrict__ b, const unsigned int* __restrict__ flag_count,
    const int* __restrict__ flag_list, float* __restrict__ out_exp,
    float* __restrict__ out_prob, float* __restrict__ out_k) {
  __shared__ double part[4][NEXP];
  const int t = threadIdx.x;
  const int e = t & 63;
  const int c = t >> 6;
  const int n = (int)*flag_count;

  for (int i = blockIdx.x; i < n; i += gridDim.x) {
    const int tok = flag_list[i];
    const float* xrow = x + (size_t)tok * HID;
    double s = 0.0;
    const int k0 = c * (HID / 4);
#pragma unroll 8
    for (int k = k0; k < k0 + HID / 4; ++k)
      s = fma((double)xrow[k], (double)W[(size_t)k * NEXP + e], s);
    part[c][e] = s;
    __syncthreads();

    if (t < 64) {
      double lgv = ((part[0][e] + part[1][e]) + part[2][e]) + part[3][e] +
                   (double)b[e];
      double mx = lgv;
#pragma unroll
      for (int off = 32; off; off >>= 1) mx = fmax(mx, __shfl_xor(mx, off));
      double ev = exp(lgv - mx);
      double sm = ev;
#pragma unroll
      for (int off = 32; off; off >>= 1) sm += __shfl_xor(sm, off);
      double p = ev / sm;

      double sp = p;
      int    si = e;
#pragma unroll
      for (int k = 2; k <= 64; k <<= 1) {
#pragma unroll
        for (int j = k >> 1; j > 0; j >>= 1) {
          double op = __shfl_xor(sp, j);
          int    oi = __shfl_xor(si, j);
          bool cmp  = (sp > op) || (sp == op && si < oi);
          bool keep = (cmp == (((e & k) == 0) == ((e & j) == 0)));
          if (!keep) { sp = op; si = oi; }
        }
      }

      double cc = sp;
#pragma unroll
      for (int off = 1; off < 64; off <<= 1) {
        double tp = __shfl_up(cc, off);
        if (e >= off) cc += tp;
      }

      unsigned long long m = __ballot(cc >= 0.8);
      int kv = (m == 0ULL) ? NEXP : __ffsll(m);

      bool sel = e < kv;
      size_t base = (size_t)tok * NEXP;
      out_exp[base + e]  = sel ? (float)si : -1.0f;
      out_prob[base + e] = sel ? (float)sp : 0.0f;
      if (e == 0) out_k[tok] = (float)kv;
    }
    __syncthreads();
  }
}

extern "C" void kernel_launch(void* const* d_in, const int* in_sizes, int n_in,
                              void* d_out, int out_size, void* d_ws,
                              size_t ws_size, hipStream_t stream) {
  const float* x = (const float*)d_in[0];
  const float* W = (const float*)d_in[1];
  const float* b = (const float*)d_in[2];

  float* out_exp  = (float*)d_out;
  float* out_prob = out_exp + (size_t)NTOK * NEXP;
  float* out_k    = out_prob + (size_t)NTOK * NEXP;

  short* wfh = (short*)d_ws;                                   // 512 KB
  short* wfl = (short*)((char*)d_ws + (size_t)512 * 1024);     // 512 KB
  unsigned int* flag_count = (unsigned int*)((char*)d_ws + (size_t)1024 * 1024);
  int* flag_list = (int*)((char*)d_ws + (size_t)1024 * 1024 + 256);

  wfrag_kernel<<<128, 256, 0, stream>>>(W, wfh, wfl, flag_count);
  gemm_route_kernel<<<NTOK / 64, 256, 0, stream>>>(
      x, wfh, wfl, b, out_exp, out_prob, out_k, flag_count, flag_list);
  router_repair<<<128, 256, 0, stream>>>(x, W, b, flag_count, flag_list,
                                         out_exp, out_prob, out_k);
}

// Round 12
// 117.413 us; speedup vs baseline: 1.1499x; 1.1499x over previous
//
#include <hip/hip_runtime.h>
#include <math.h>

#define HID 4096
#define NEXP 64
#define NTOK 16384

typedef __attribute__((ext_vector_type(8))) short short8;
typedef __attribute__((ext_vector_type(8))) __bf16 bf16x8;
typedef __attribute__((ext_vector_type(4))) float f32x4;

// ---- Kernel 0: W[k][e] fp32 -> hi/lo bf16, B-fragment-linear (also zeroes
// the flag counter so no memset node is needed in the graph).
__global__ __launch_bounds__(256) void wfrag_kernel(
    const float* __restrict__ W, short* __restrict__ wfh,
    short* __restrict__ wfl, unsigned int* __restrict__ flag_count) {
  if (blockIdx.x == 0 && threadIdx.x == 0) *flag_count = 0u;
  int gid = blockIdx.x * 256 + threadIdx.x;  // 0 .. 32767
  int l  = gid & 63;
  int nt = (gid >> 6) & 3;
  int ks = gid >> 8;                         // 0 .. 127 (K=32 slice)
  int e  = nt * 16 + (l & 15);
  int k0 = ks * 32 + (l >> 4) * 8;
  bf16x8 h8, l8;
#pragma unroll
  for (int j = 0; j < 8; ++j) {
    float w = W[(size_t)(k0 + j) * NEXP + e];
    __bf16 h = (__bf16)w;         // RNE
    h8[j] = h;
    l8[j] = (__bf16)(w - (float)h);
  }
  ((short8*)wfh)[gid] = __builtin_bit_cast(short8, h8);
  ((short8*)wfl)[gid] = __builtin_bit_cast(short8, l8);
}

// ---------------- gemm helpers (parity P is a compile-time literal) ---------
template <int P>
__device__ __forceinline__ void issue_b(const short8*& wh, const short8*& wl,
                                        short8 (&rbh)[2][4],
                                        short8 (&rbl)[2][4]) {
#pragma unroll
  for (int nt = 0; nt < 4; ++nt) {
    rbh[P][nt] = wh[nt * 64];
    rbl[P][nt] = wl[nt * 64];
  }
  wh += 256;
  wl += 256;
}

template <int P>
__device__ __forceinline__ void issue_g(const float* (&xp)[4][2],
                                        float* wavebase /* smem + w*4096 */) {
#pragma unroll
  for (int st = 0; st < 4; ++st)
#pragma unroll
    for (int p = 0; p < 2; ++p)
      __builtin_amdgcn_global_load_lds(xp[st][p],
                                       wavebase + P * 2048 + st * 512 + p * 256,
                                       16, 0, 0);
#pragma unroll
  for (int st = 0; st < 4; ++st) {
    xp[st][0] += 32;
    xp[st][1] += 32;
  }
}

template <int P>
__device__ __forceinline__ void compute_c(const float* wavebase,
                                          short8 (&rbh)[2][4],
                                          short8 (&rbl)[2][4],
                                          f32x4 (&acc)[4][4], int l) {
  const int lr = l >> 4;
  const int s0 = ((2 * lr) ^ (l & 7)) * 16;
  const char* cb = (const char*)(wavebase + P * 2048);
#pragma unroll
  for (int st = 0; st < 4; ++st) {
    const char* rowbase =
        cb + st * 2048 + ((l >> 3) & 1) * 1024 + (l & 7) * 128;
    float4 lo = *(const float4*)(rowbase + s0);
    float4 hi = *(const float4*)(rowbase + (s0 ^ 16));
    float xv[8] = {lo.x, lo.y, lo.z, lo.w, hi.x, hi.y, hi.z, hi.w};
    bf16x8 ah, al;
#pragma unroll
    for (int j = 0; j < 8; ++j) {
      __bf16 h = (__bf16)xv[j];
      ah[j] = h;
      al[j] = (__bf16)(xv[j] - (float)h);
    }
#pragma unroll
    for (int nt = 0; nt < 4; ++nt) {
      bf16x8 vh = __builtin_bit_cast(bf16x8, rbh[P][nt]);
      bf16x8 vl = __builtin_bit_cast(bf16x8, rbl[P][nt]);
      acc[st][nt] = __builtin_amdgcn_mfma_f32_16x16x32_bf16(ah, vh, acc[st][nt], 0, 0, 0);
      acc[st][nt] = __builtin_amdgcn_mfma_f32_16x16x32_bf16(al, vh, acc[st][nt], 0, 0, 0);
      acc[st][nt] = __builtin_amdgcn_mfma_f32_16x16x32_bf16(ah, vl, acc[st][nt], 0, 0, 0);
      acc[st][nt] = __builtin_amdgcn_mfma_f32_16x16x32_bf16(al, vl, acc[st][nt], 0, 0, 0);
    }
  }
}

#define SB __builtin_amdgcn_sched_barrier(0)
#define WAIT16 asm volatile("s_waitcnt vmcnt(16)" ::: "memory")
#define WAIT0  asm volatile("s_waitcnt vmcnt(0)" ::: "memory")

// ---- Kernel 1: MFMA GEMM. 512 threads = 8 waves = 8 K-eighths x 64 tokens.
// 2 waves/SIMD (TLP hides the per-wave load/wait stalls R11 exposed).
// Chunk = K=32: 8 B-loads + 8 glds feed 64 MFMAs; counted-vmcnt pipeline
// (WAIT16 keeps exactly next chunk's B+glds in flight; vmcnt(0) only at end).
// Epilogue: waves 4-7 park tiles in LDS, waves 0-3 add -> 4 global partials.
__global__ __launch_bounds__(512, 2) void gemm_kernel(
    const float* __restrict__ x, const short* __restrict__ wfh,
    const short* __restrict__ wfl, float* __restrict__ partial) {
  __shared__ float smem[32768];  // 128 KB: [8 waves][2 parity][2048 floats]

  const int t = threadIdx.x;
  const int w = t >> 6;    // wave = K-eighth
  const int l = t & 63;
  const int lr = l >> 4;
  const int m0 = blockIdx.x * 64;
  const int kq = w * (HID / 8);

  float* wavebase = smem + w * 4096;

  // glds sources: subtile st, half p: row = m0+st*16+8p+(l>>3),
  // pre-swizzled granule g = (l&7)^(l>>3)  (read side XORs the same).
  const float* xp[4][2];
#pragma unroll
  for (int st = 0; st < 4; ++st)
#pragma unroll
    for (int p = 0; p < 2; ++p) {
      int g = (l & 7) ^ (l >> 3);
      int row = m0 + st * 16 + 8 * p + (l >> 3);
      xp[st][p] = x + (size_t)row * HID + kq + g * 4;
    }

  const short8* wh = (const short8*)wfh + (size_t)(w * 16 * 4) * 64 + l;
  const short8* wl = (const short8*)wfl + (size_t)(w * 16 * 4) * 64 + l;

  f32x4 acc[4][4];
#pragma unroll
  for (int st = 0; st < 4; ++st)
#pragma unroll
    for (int nt = 0; nt < 4; ++nt) acc[st][nt] = (f32x4){0.f, 0.f, 0.f, 0.f};

  short8 rbh[2][4], rbl[2][4];

  // prologue: chunk 0 -> parity 0 (B first: oldest in vmcnt stream)
  issue_b<0>(wh, wl, rbh, rbl);
  SB;
  issue_g<0>(xp, wavebase);
  SB;

#pragma unroll 1
  for (int c2 = 0; c2 < 7; ++c2) {  // chunks 2*c2, 2*c2+1
    issue_b<1>(wh, wl, rbh, rbl);
    SB;
    issue_g<1>(xp, wavebase);
    SB;
    WAIT16;
    SB;
    compute_c<0>(wavebase, rbh, rbl, acc, l);

    issue_b<0>(wh, wl, rbh, rbl);
    SB;
    issue_g<0>(xp, wavebase);
    SB;
    WAIT16;
    SB;
    compute_c<1>(wavebase, rbh, rbl, acc, l);
  }
  // chunk 14: issue 15, drain 14, compute 14; then drain+compute 15
  issue_b<1>(wh, wl, rbh, rbl);
  SB;
  issue_g<1>(xp, wavebase);
  SB;
  WAIT16;
  SB;
  compute_c<0>(wavebase, rbh, rbl, acc, l);
  WAIT0;
  SB;
  compute_c<1>(wavebase, rbh, rbl, acc, l);

  // ---- pairwise reduce: wave w>=4 parks tile, wave w<4 adds + stores ----
  __syncthreads();
  float* red = smem;  // [4][64][68] = 69.6 KB (overlays staging, post-barrier)
  if (w >= 4) {
#pragma unroll
    for (int st = 0; st < 4; ++st)
#pragma unroll
      for (int nt = 0; nt < 4; ++nt)
#pragma unroll
        for (int r = 0; r < 4; ++r)
          red[((w - 4) * 64 + st * 16 + lr * 4 + r) * 68 + nt * 16 +
              (l & 15)] = acc[st][nt][r];
  }
  __syncthreads();
  if (w < 4) {
#pragma unroll
    for (int st = 0; st < 4; ++st)
#pragma unroll
      for (int nt = 0; nt < 4; ++nt)
#pragma unroll
        for (int r = 0; r < 4; ++r) {
          int row = st * 16 + lr * 4 + r;
          float s = acc[st][nt][r] +
                    red[(w * 64 + row) * 68 + nt * 16 + (l & 15)];
          partial[((size_t)w * NTOK + m0 + row) * NEXP + nt * 16 + (l & 15)] =
              s;
        }
  }
}

// ---- Kernel 2: sum partials + fp32 routing (1 token per wave) --------------
__global__ __launch_bounds__(256) void route_kernel(
    const float* __restrict__ partial, const float* __restrict__ b,
    float* __restrict__ out_exp, float* __restrict__ out_prob,
    float* __restrict__ out_k, unsigned int* __restrict__ flag_count,
    int* __restrict__ flag_list) {
  const int tok = (int)((blockIdx.x * 256 + threadIdx.x) >> 6);
  const int l   = threadIdx.x & 63;

  float p0 = partial[((size_t)0 * NTOK + tok) * NEXP + l];
  float p1 = partial[((size_t)1 * NTOK + tok) * NEXP + l];
  float p2 = partial[((size_t)2 * NTOK + tok) * NEXP + l];
  float p3 = partial[((size_t)3 * NTOK + tok) * NEXP + l];
  float lgv = (p0 + p1) + (p2 + p3) + b[l];

  float mx = lgv;
#pragma unroll
  for (int off = 32; off; off >>= 1) mx = fmaxf(mx, __shfl_xor(mx, off));
  float ev = expf(lgv - mx);
  float sm = ev;
#pragma unroll
  for (int off = 32; off; off >>= 1) sm += __shfl_xor(sm, off);
  float p = ev / sm;

  // bitonic sort: descending by p, ties by ascending index
  float sp = p;
  int   si = l;
#pragma unroll
  for (int k = 2; k <= 64; k <<= 1) {
#pragma unroll
    for (int j = k >> 1; j > 0; j >>= 1) {
      float op = __shfl_xor(sp, j);
      int   oi = __shfl_xor(si, j);
      bool cmp  = (sp > op) || (sp == op && si < oi);
      bool keep = (cmp == (((l & k) == 0) == ((l & j) == 0)));
      if (!keep) { sp = op; si = oi; }
    }
  }

  // inclusive prefix sum
  float c = sp;
#pragma unroll
  for (int off = 1; off < 64; off <<= 1) {
    float tp = __shfl_up(c, off);
    if (l >= off) c += tp;
  }

  unsigned long long m = __ballot(c >= 0.8f);
  int kv = (m == 0ULL) ? NEXP : __ffsll(m);

  // ambiguity flags (margins >> split-bf16 logit error ~2e-5)
  float spn = __shfl_down(sp, 1);
  bool pairRisk = (l < kv) && (l < 63) && ((sp - spn) < 1e-3f * (sp + spn));
  bool cumRisk  = fabsf(c - 0.8f) < 3e-4f;
  bool flagged  = (__ballot(pairRisk || cumRisk) != 0ULL);

  bool sel = l < kv;
  size_t base = (size_t)tok * NEXP;
  out_exp[base + l]  = sel ? (float)si : -1.0f;
  out_prob[base + l] = sel ? sp : 0.0f;
  if (l == 0) {
    out_k[tok] = (float)kv;
    if (flagged) {
      unsigned int idx = atomicAdd(flag_count, 1u);
      flag_list[idx] = tok;
    }
  }
}

// ---- Kernel 3: fp64 exact repair of flagged tokens -------------------------
__global__ __launch_bounds__(256) void router_repair(
    const float* __restrict__ x, const float* __restrict__ W,
    const float* __restrict__ b, const unsigned int* __restrict__ flag_count,
    const int* __restrict__ flag_list, float* __restrict__ out_exp,
    float* __restrict__ out_prob, float* __restrict__ out_k) {
  __shared__ double part[4][NEXP];
  const int t = threadIdx.x;
  const int e = t & 63;
  const int c = t >> 6;
  const int n = (int)*flag_count;

  for (int i = blockIdx.x; i < n; i += gridDim.x) {
    const int tok = flag_list[i];
    const float* xrow = x + (size_t)tok * HID;
    double s = 0.0;
    const int k0 = c * (HID / 4);
#pragma unroll 8
    for (int k = k0; k < k0 + HID / 4; ++k)
      s = fma((double)xrow[k], (double)W[(size_t)k * NEXP + e], s);
    part[c][e] = s;
    __syncthreads();

    if (t < 64) {
      double lgv = ((part[0][e] + part[1][e]) + part[2][e]) + part[3][e] +
                   (double)b[e];
      double mx = lgv;
#pragma unroll
      for (int off = 32; off; off >>= 1) mx = fmax(mx, __shfl_xor(mx, off));
      double ev = exp(lgv - mx);
      double sm = ev;
#pragma unroll
      for (int off = 32; off; off >>= 1) sm += __shfl_xor(sm, off);
      double p = ev / sm;

      double sp = p;
      int    si = e;
#pragma unroll
      for (int k = 2; k <= 64; k <<= 1) {
#pragma unroll
        for (int j = k >> 1; j > 0; j >>= 1) {
          double op = __shfl_xor(sp, j);
          int    oi = __shfl_xor(si, j);
          bool cmp  = (sp > op) || (sp == op && si < oi);
          bool keep = (cmp == (((e & k) == 0) == ((e & j) == 0)));
          if (!keep) { sp = op; si = oi; }
        }
      }

      double cc = sp;
#pragma unroll
      for (int off = 1; off < 64; off <<= 1) {
        double tp = __shfl_up(cc, off);
        if (e >= off) cc += tp;
      }

      unsigned long long m = __ballot(cc >= 0.8);
      int kv = (m == 0ULL) ? NEXP : __ffsll(m);

      bool sel = e < kv;
      size_t base = (size_t)tok * NEXP;
      out_exp[base + e]  = sel ? (float)si : -1.0f;
      out_prob[base + e] = sel ? (float)sp : 0.0f;
      if (e == 0) out_k[tok] = (float)kv;
    }
    __syncthreads();
  }
}

extern "C" void kernel_launch(void* const* d_in, const int* in_sizes, int n_in,
                              void* d_out, int out_size, void* d_ws,
                              size_t ws_size, hipStream_t stream) {
  const float* x = (const float*)d_in[0];
  const float* W = (const float*)d_in[1];
  const float* b = (const float*)d_in[2];

  float* out_exp  = (float*)d_out;
  float* out_prob = out_exp + (size_t)NTOK * NEXP;
  float* out_k    = out_prob + (size_t)NTOK * NEXP;

  short* wfh = (short*)d_ws;                                   // 512 KB
  short* wfl = (short*)((char*)d_ws + (size_t)512 * 1024);     // 512 KB
  unsigned int* flag_count = (unsigned int*)((char*)d_ws + (size_t)1024 * 1024);
  int* flag_list = (int*)((char*)d_ws + (size_t)1024 * 1024 + 256);
  float* partial = (float*)((char*)d_ws + (size_t)2 * 1024 * 1024);  // 16 MB

  wfrag_kernel<<<128, 256, 0, stream>>>(W, wfh, wfl, flag_count);
  gemm_kernel<<<NTOK / 64, 512, 0, stream>>>(x, wfh, wfl, partial);
  route_kernel<<<NTOK * NEXP / 256, 256, 0, stream>>>(
      partial, b, out_exp, out_prob, out_k, flag_count, flag_list);
  router_repair<<<128, 256, 0, stream>>>(x, W, b, flag_count, flag_list,
                                         out_exp, out_prob, out_k);
}